// Round 19
// baseline (43.047 us; speedup 1.0000x reference)
//
#include <hip/hip_runtime.h>
#include <climits>

#define HH 1024
#define WW 1024
#define DD 128
#define NPIX (HH * WW)
#define NBB 1024   // kA stats blocks AND kB main blocks: 1 row each, same grid

// ROUND 19 = ROUND 18 byte-identical, except the (kC1,kC2) tail pair is
// launched THREE times. Both are idempotent; (dur_us - 32.0)/2 measures the
// marginal cost of one tail pair -- the quantity that decides between model
// M1 (tail ~3.5us, kB-first cold ~24us) and M2 (tail ~12us, form-invariant).

// ws 4B-unit layout:
//   wsf[64..576)    M (4x128 row-major)
//   wsf[576..704)   c (128)
//   wsi[1024..2048) rminP | [2048..3072) rmaxP | [3072..4096) cminP
//   wsi[4096..5120) cmaxP | [5120..6144) cntP      (one per ROW)
//   wsf[6400..8448) m padded: m[f] at wsf[6400 + f*16]
//   wsf[8448..9472) keep-alive dummies | wsf[9600..9856) W3-warm dummies
//   wsf[16384..)    partials, layout [block][feature]
#define RMINP 1024
#define RMAXP 2048
#define CMINP 3072
#define CMAXP 4096
#define CNTP  5120
#define MPAD  6400
#define XWARM 8448
#define WWARM 9600
#define PART  16384

typedef __attribute__((ext_vector_type(2))) float f32x2;

// ---- kA: 1024 row-blocks (stats + row warm) + 1 prep block -----------------
__global__ __launch_bounds__(256) void kA(const float* __restrict__ x0,
                                          const float* __restrict__ x1,
                                          const float* __restrict__ W1,
                                          const float* __restrict__ b1,
                                          const float* __restrict__ W2,
                                          const float* __restrict__ b2,
                                          const float* __restrict__ W3,
                                          float* __restrict__ wsf,
                                          int* __restrict__ wsi) {
    __shared__ int sred[4][4];
    int blk = blockIdx.x, tid = threadIdx.x;
    int wv = tid >> 6, lane = tid & 63;

    if (blk < NBB) {
        const float4* x04 = (const float4*)(x0) + (size_t)blk * 256;
        const float4* x14 = (const float4*)(x1) + (size_t)blk * 256;
        float4 va = x04[tid];
        float4 vb = x14[tid];

        bool z0 = va.x != 0.f, z1 = va.y != 0.f, z2 = va.z != 0.f, z3 = va.w != 0.f;
        int any = (int)(z0 | z1 | z2 | z3);
        int c4 = 4 * tid;
        int cmn = any ? (z0 ? c4 : (z1 ? c4 + 1 : (z2 ? c4 + 2 : c4 + 3))) : INT_MAX;
        int cmx = any ? (z3 ? c4 + 3 : (z2 ? c4 + 2 : (z1 ? c4 + 1 : c4))) : -1;
        int cnt = (int)z0 + (int)z1 + (int)z2 + (int)z3;
        for (int off = 32; off >= 1; off >>= 1) {
            cmn = min(cmn, __shfl_xor(cmn, off, 64));
            cmx = max(cmx, __shfl_xor(cmx, off, 64));
            cnt += __shfl_xor(cnt, off, 64);
            any |= __shfl_xor(any, off, 64);
        }
        if (lane == 0) {
            sred[wv][0] = cmn; sred[wv][1] = cmx;
            sred[wv][2] = cnt; sred[wv][3] = any;
        }
        __syncthreads();
        if (tid == 0) {
            int a = sred[0][0], b = sred[0][1], c = sred[0][2], d = sred[0][3];
            for (int w = 1; w < 4; ++w) {
                a = min(a, sred[w][0]); b = max(b, sred[w][1]);
                c += sred[w][2];        d |= sred[w][3];
            }
            wsi[CMINP + blk] = a;
            wsi[CMAXP + blk] = b;
            wsi[CNTP  + blk] = c;
            wsi[RMINP + blk] = d ? blk : INT_MAX;
            wsi[RMAXP + blk] = d ? blk : -1;
        }
        float s = (vb.x + vb.y) + (vb.z + vb.w);
        if (__float_as_uint(s) == 0x7F123456u) wsf[XWARM + (tid & 255)] = s;
        return;
    }

    if (tid < 128) {
        int j = tid;
        float p0 = 0.f, p1 = 0.f, p2 = 0.f, p3 = 0.f, cc = 0.f;
        #pragma unroll 8
        for (int d = 0; d < DD; ++d) {
            float w2 = W2[d * DD + j];
            p0 = fmaf(W1[0 * DD + d], w2, p0);
            p1 = fmaf(W1[1 * DD + d], w2, p1);
            p2 = fmaf(W1[2 * DD + d], w2, p2);
            p3 = fmaf(W1[3 * DD + d], w2, p3);
            cc = fmaf(b1[d],          w2, cc);
        }
        wsf[64 + 0 * DD + j] = p0;
        wsf[64 + 1 * DD + j] = p1;
        wsf[64 + 2 * DD + j] = p2;
        wsf[64 + 3 * DD + j] = p3;
        wsf[576 + j] = cc + b2[j];
    } else {
        const float4* w34 = (const float4*)W3;
        float s = 0.f;
        for (int k = tid - 128; k < DD * DD / 4; k += 128) {
            float4 t4 = w34[k]; s += t4.x + t4.y + t4.z + t4.w;
        }
        wsf[WWARM + tid - 128] = s;
    }
}

// ---- kB: main accumulate (R14/R16-proven core), 1 row/block ----------------
__global__ __launch_bounds__(256) void kB(const float* __restrict__ x0,
                                          const float* __restrict__ x1,
                                          float* __restrict__ wsf,
                                          const int* __restrict__ wsi) {
    __shared__ float sv_f[4096];
    __shared__ unsigned short lidx[1024];
    __shared__ int   lcnt;
    __shared__ int   sred[4][4];
    __shared__ float fred[128][9];

    int tid = threadIdx.x, blk = blockIdx.x;
    int wv = tid >> 6, lane = tid & 63;

    if (tid == 0) lcnt = 0;

    int rmn = INT_MAX, rmx = -1, cmn = INT_MAX, cmx = -1;
    #pragma unroll
    for (int k = 0; k < 4; ++k) {
        int i = tid + 256 * k;
        rmn = min(rmn, wsi[RMINP + i]);
        rmx = max(rmx, wsi[RMAXP + i]);
        cmn = min(cmn, wsi[CMINP + i]);
        cmx = max(cmx, wsi[CMAXP + i]);
    }
    for (int off = 32; off >= 1; off >>= 1) {
        rmn = min(rmn, __shfl_xor(rmn, off, 64));
        rmx = max(rmx, __shfl_xor(rmx, off, 64));
        cmn = min(cmn, __shfl_xor(cmn, off, 64));
        cmx = max(cmx, __shfl_xor(cmx, off, 64));
    }
    if (lane == 0) {
        sred[wv][0] = rmn; sred[wv][1] = rmx;
        sred[wv][2] = cmn; sred[wv][3] = cmx;
    }
    __syncthreads();
    rmn = min(min(sred[0][0], sred[1][0]), min(sred[2][0], sred[3][0]));
    rmx = max(max(sred[0][1], sred[1][1]), max(sred[2][1], sred[3][1]));
    cmn = min(min(sred[0][2], sred[1][2]), min(sred[2][2], sred[3][2]));
    cmx = max(max(sred[0][3], sred[1][3]), max(sred[2][3], sred[3][3]));

    const float4* x04 = (const float4*)(x0) + (size_t)blk * 256;
    const float4* x14 = (const float4*)(x1) + (size_t)blk * 256;
    float4* sv4 = (float4*)sv_f;
    {
        float4 va = x04[tid];
        float4 vb = x14[tid];
        sv4[2 * tid]     = make_float4(va.x, va.y, vb.x, vb.y);
        sv4[2 * tid + 1] = make_float4(va.z, va.w, vb.z, vb.w);
        int p4 = 4 * tid;
        if (va.x == 0.f) { int p = atomicAdd(&lcnt, 1); lidx[p] = (unsigned short)(p4 + 0); }
        if (va.y == 0.f) { int p = atomicAdd(&lcnt, 1); lidx[p] = (unsigned short)(p4 + 1); }
        if (va.z == 0.f) { int p = atomicAdd(&lcnt, 1); lidx[p] = (unsigned short)(p4 + 2); }
        if (va.w == 0.f) { int p = atomicAdd(&lcnt, 1); lidx[p] = (unsigned short)(p4 + 3); }
    }
    __syncthreads();

    int ft = tid & 31;
    int cq = tid >> 5;
    int row = blk;
    float rs = 1.0f / (float)(rmx - rmn);
    float cs = 1.0f / (float)(cmx - cmn);

    f32x2 M2v[4], M3v[4], tv[4], st[4], acc[4];
    float a1v[4], rb[4];
    float accsub[4];
    #pragma unroll
    for (int k = 0; k < 4; ++k) {
        int f = ft + 32 * k;
        float M2 = wsf[64 + 2 * DD + f];
        float M3 = wsf[64 + 3 * DD + f];
        float a0 = wsf[64 + 0 * DD + f] * rs;
        float a1 = wsf[64 + 1 * DD + f] * cs;
        float cp = wsf[576 + f] - (float)rmn * a0 - (float)cmn * a1;
        rb[k]  = fmaf((float)row, a0, cp);
        a1v[k] = a1;
        float tA = fmaf((float)(cq * 128), a1, rb[k]);
        M2v[k] = (f32x2)M2;
        M3v[k] = (f32x2)M3;
        tv[k].x = tA; tv[k].y = tA + a1;
        st[k] = (f32x2)(a1 + a1);
        acc[k] = (f32x2)0.f;
        accsub[k] = 0.f;
    }

    const float4* p = sv4 + cq * 64;
    float4 vq = p[0];
    #pragma unroll 4
    for (int q = 0; q < 64; ++q) {
        float4 vn = p[(q + 1) & 63];
        f32x2 v0; v0.x = vq.x; v0.y = vq.y;
        f32x2 v1; v1.x = vq.z; v1.y = vq.w;
        #pragma unroll
        for (int k = 0; k < 4; ++k) {
            f32x2 d = __builtin_elementwise_fma(v0, M2v[k],
                        __builtin_elementwise_fma(v1, M3v[k], tv[k]));
            f32x2 r = __builtin_elementwise_max(d, (f32x2)0.f);
            acc[k] += r;
            tv[k] += st[k];
        }
        vq = vn;
    }

    int nz = lcnt;
    for (int ii = 0; ii < nz; ++ii) {
        int px = lidx[ii];
        if ((px >> 7) == cq) {
            float v0 = sv_f[(px >> 1) * 4 + (px & 1)];
            float v1 = sv_f[(px >> 1) * 4 + 2 + (px & 1)];
            #pragma unroll
            for (int k = 0; k < 4; ++k) {
                float tp = fmaf((float)px, a1v[k], rb[k]);
                accsub[k] += fmaxf(fmaf(v0, M2v[k].x, fmaf(v1, M3v[k].x, tp)), 0.f);
            }
        }
    }

    #pragma unroll
    for (int k = 0; k < 4; ++k)
        fred[ft + 32 * k][cq] = (acc[k].x + acc[k].y) - accsub[k];
    __syncthreads();
    if (tid < 128) {
        const float* fr = fred[tid];
        float s = ((fr[0] + fr[1]) + (fr[2] + fr[3]))
                + ((fr[4] + fr[5]) + (fr[6] + fr[7]));
        wsf[PART + (size_t)blk * DD + tid] = s;
    }
}

// ---- kC1: 128 blocks, block f: sum partials[b][f] + count -> m_pad[f*16] ---
__global__ __launch_bounds__(256) void kC1(float* __restrict__ wsf,
                                           const int* __restrict__ wsi) {
    __shared__ float sred[4];
    __shared__ int   cred[4];
    int f = blockIdx.x, tid = threadIdx.x;
    int wv = tid >> 6, lane = tid & 63;

    int c = 0;
    #pragma unroll
    for (int k = 0; k < 4; ++k) c += wsi[CNTP + tid + 256 * k];
    for (int off = 32; off >= 1; off >>= 1) c += __shfl_xor(c, off, 64);
    if (lane == 0) cred[wv] = c;

    const float* p = wsf + PART + f;
    float S = 0.f;
    #pragma unroll
    for (int k = 0; k < 4; ++k) S += p[(size_t)(tid + 256 * k) * DD];
    for (int off = 32; off >= 1; off >>= 1) S += __shfl_xor(S, off, 64);
    if (lane == 0) sred[wv] = S;
    __syncthreads();
    if (tid == 0) {
        float tot = (sred[0] + sred[1]) + (sred[2] + sred[3]);
        float cnt = (float)(cred[0] + cred[1] + cred[2] + cred[3]);
        wsf[MPAD + f * 16] = tot / cnt;
    }
}

// ---- kC2: 1 block, 256 threads: out = b3 + m @ W3 --------------------------
__global__ __launch_bounds__(256) void kC2(const float* __restrict__ wsf,
                                           const float* __restrict__ W3,
                                           const float* __restrict__ b3,
                                           float* __restrict__ out) {
    __shared__ float sm[128];
    __shared__ float s2[256];
    int tid = threadIdx.x;
    if (tid < 128) sm[tid] = wsf[MPAD + tid * 16];
    __syncthreads();

    int col = tid & 127, h = tid >> 7;
    float o = 0.f;
    #pragma unroll 8
    for (int d = h * 64; d < h * 64 + 64; ++d)
        o = fmaf(sm[d], W3[d * DD + col], o);
    s2[tid] = o;
    __syncthreads();
    if (tid < 128) out[tid] = b3[tid] + s2[tid] + s2[tid + 128];
}

extern "C" void kernel_launch(void* const* d_in, const int* in_sizes, int n_in,
                              void* d_out, int out_size, void* d_ws, size_t ws_size,
                              hipStream_t stream) {
    const float* x  = (const float*)d_in[0];
    const float* x0 = x;
    const float* x1 = x + NPIX;
    const float* W1 = (const float*)d_in[1];
    const float* b1 = (const float*)d_in[2];
    const float* W2 = (const float*)d_in[3];
    const float* b2 = (const float*)d_in[4];
    const float* W3 = (const float*)d_in[5];
    const float* b3 = (const float*)d_in[6];
    float* outp = (float*)d_out;
    float* wsf  = (float*)d_ws;
    int*   wsi  = (int*)d_ws;

    hipLaunchKernelGGL(kA, dim3(NBB + 1), dim3(256), 0, stream,
                       x0, x1, W1, b1, W2, b2, W3, wsf, wsi);
    hipLaunchKernelGGL(kB, dim3(NBB), dim3(256), 0, stream, x0, x1, wsf, wsi);
    // MEASUREMENT: tail pair x3 (idempotent). (dur_us - 32.0)/2 = one tail pair.
    hipLaunchKernelGGL(kC1, dim3(DD), dim3(256), 0, stream, wsf, wsi);
    hipLaunchKernelGGL(kC2, dim3(1), dim3(256), 0, stream, wsf, W3, b3, outp);
    hipLaunchKernelGGL(kC1, dim3(DD), dim3(256), 0, stream, wsf, wsi);
    hipLaunchKernelGGL(kC2, dim3(1), dim3(256), 0, stream, wsf, W3, b3, outp);
    hipLaunchKernelGGL(kC1, dim3(DD), dim3(256), 0, stream, wsf, wsi);
    hipLaunchKernelGGL(kC2, dim3(1), dim3(256), 0, stream, wsf, W3, b3, outp);
}

// Round 20
// 34.584 us; speedup vs baseline: 1.2447x; 1.2447x over previous
//
#include <hip/hip_runtime.h>
#include <climits>

#define HH 1024
#define WW 1024
#define DD 128
#define NPIX (HH * WW)
#define NSB 256    // stats blocks (4 rows each) in kA
#define NBB 1024   // main blocks (1 row each) in kB

// ws 4B-unit layout (R14 base):
//   wsf[64..576)    M (4x128 row-major)
//   wsf[576..704)   c (128)
//   wsi[1024..1280) rminP | [1280..1536) rmaxP | [1536..1792) cminP
//   wsi[1792..2048) cmaxP | [2048..2304) cntP     (one per stats block)
//   wsf[6400..6656) x1-warm dummies
//   wsf[8192..8192+128*1024) partials, layout [feature][block]
#define RMINP 1024
#define RMAXP 1280
#define CMINP 1536
#define CMAXP 1792
#define CNTP  2048
#define PART  8192

typedef __attribute__((ext_vector_type(2))) float f32x2;

// guaranteed packed-f32 math (no reliance on compiler vectorization)
__device__ __forceinline__ f32x2 pk_fma(f32x2 a, f32x2 b, f32x2 c) {
    f32x2 d;
    asm("v_pk_fma_f32 %0, %1, %2, %3" : "=v"(d) : "v"(a), "v"(b), "v"(c));
    return d;
}
__device__ __forceinline__ f32x2 pk_add(f32x2 a, f32x2 b) {
    f32x2 d;
    asm("v_pk_add_f32 %0, %1, %2" : "=v"(d) : "v"(a), "v"(b));
    return d;
}

// ---- stats for a block's 4 rows (proven rounds 4-19) -----------------------
__device__ __forceinline__ void d_stats(const float* __restrict__ x0, int blk,
                                        int tid, int* __restrict__ wsi,
                                        int (*sred)[8]) {
    const float4* x4 = (const float4*)(x0) + (size_t)blk * 1024;
    int any0, any1, any2, any3;
    int cmn = INT_MAX, cmx = -1, cnt = 0;
    int c4 = 4 * tid;
    {
        float4 v;
        bool z0, z1, z2, z3;
        #define STAT_K(K, ANY)                                                 \
            v = x4[K * 256 + tid];                                             \
            z0 = v.x != 0.f; z1 = v.y != 0.f; z2 = v.z != 0.f; z3 = v.w != 0.f;\
            ANY = (int)(z0 | z1 | z2 | z3);                                    \
            if (ANY) {                                                         \
                cmn = min(cmn, z0 ? c4 : (z1 ? c4+1 : (z2 ? c4+2 : c4+3)));    \
                cmx = max(cmx, z3 ? c4+3 : (z2 ? c4+2 : (z1 ? c4+1 : c4)));    \
            }                                                                  \
            cnt += (int)z0 + (int)z1 + (int)z2 + (int)z3;
        STAT_K(0, any0) STAT_K(1, any1) STAT_K(2, any2) STAT_K(3, any3)
        #undef STAT_K
    }
    for (int off = 32; off >= 1; off >>= 1) {
        cmn = min(cmn, __shfl_xor(cmn, off, 64));
        cmx = max(cmx, __shfl_xor(cmx, off, 64));
        cnt += __shfl_xor(cnt, off, 64);
        any0 |= __shfl_xor(any0, off, 64);
        any1 |= __shfl_xor(any1, off, 64);
        any2 |= __shfl_xor(any2, off, 64);
        any3 |= __shfl_xor(any3, off, 64);
    }
    int wave = tid >> 6;
    if ((tid & 63) == 0) {
        sred[wave][0] = cmn; sred[wave][1] = cmx; sred[wave][2] = cnt;
        sred[wave][3] = any0; sred[wave][4] = any1;
        sred[wave][5] = any2; sred[wave][6] = any3;
    }
    __syncthreads();
    if (tid == 0) {
        int a = sred[0][0], b = sred[0][1], c = sred[0][2];
        int f0 = sred[0][3], f1 = sred[0][4], f2 = sred[0][5], f3 = sred[0][6];
        for (int w = 1; w < 4; ++w) {
            a = min(a, sred[w][0]); b = max(b, sred[w][1]); c += sred[w][2];
            f0 |= sred[w][3]; f1 |= sred[w][4]; f2 |= sred[w][5]; f3 |= sred[w][6];
        }
        int r0 = blk * 4;
        wsi[RMINP + blk] = f0 ? r0 : (f1 ? r0+1 : (f2 ? r0+2 : (f3 ? r0+3 : INT_MAX)));
        wsi[RMAXP + blk] = f3 ? r0+3 : (f2 ? r0+2 : (f1 ? r0+1 : (f0 ? r0 : -1)));
        wsi[CMINP + blk] = a;
        wsi[CMAXP + blk] = b;
        wsi[CNTP  + blk] = c;
    }
}

// ---- kA: 256 stats blocks (also warm x1 into L3) + 1 prep block ------------
__global__ __launch_bounds__(256) void kA(const float* __restrict__ x0,
                                          const float* __restrict__ x1,
                                          const float* __restrict__ W1,
                                          const float* __restrict__ b1,
                                          const float* __restrict__ W2,
                                          const float* __restrict__ b2,
                                          const float* __restrict__ b3,
                                          float* __restrict__ out,
                                          float* __restrict__ wsf,
                                          int* __restrict__ wsi) {
    __shared__ int sred[4][8];
    int blk = blockIdx.x, tid = threadIdx.x;
    if (blk < NSB) {
        d_stats(x0, blk, tid, wsi, sred);
        const float4* y4 = (const float4*)(x1) + (size_t)blk * 1024;
        float s = 0.f;
        #pragma unroll
        for (int k = 0; k < 4; ++k) {
            float4 t4 = y4[k * 256 + tid];
            s += (t4.x + t4.y) + (t4.z + t4.w);
        }
        if (tid == 0) wsf[6400 + blk] = s;   // keep warm loads live
        return;
    }
    if (tid < 128) {
        int j = tid;
        float p0 = 0.f, p1 = 0.f, p2 = 0.f, p3 = 0.f, cc = 0.f;
        #pragma unroll 8
        for (int d = 0; d < DD; ++d) {
            float w2 = W2[d * DD + j];
            p0 = fmaf(W1[0 * DD + d], w2, p0);
            p1 = fmaf(W1[1 * DD + d], w2, p1);
            p2 = fmaf(W1[2 * DD + d], w2, p2);
            p3 = fmaf(W1[3 * DD + d], w2, p3);
            cc = fmaf(b1[d],          w2, cc);
        }
        wsf[64 + 0 * DD + j] = p0;
        wsf[64 + 1 * DD + j] = p1;
        wsf[64 + 2 * DD + j] = p2;
        wsf[64 + 3 * DD + j] = p3;
        wsf[576 + j] = cc + b2[j];
        out[j] = b3[j];              // seed output; kC accumulates atomically
    }
}

// ---- kB: main accumulate, 1 row/block, 4 features/thread -------------------
// Changes vs R14: (1) inline-asm v_pk_fma_f32 / v_pk_add_f32 guarantee packed
// f32 math; (2) T14 prologue hoist: x-row loads + raw coefficient loads are
// issued BEFORE the stats pre-reduce so their latency hides under it.
__global__ __launch_bounds__(256) void kB(const float* __restrict__ x0,
                                          const float* __restrict__ x1,
                                          float* __restrict__ wsf,
                                          const int* __restrict__ wsi) {
    __shared__ float sv_f[4096];           // de-interleaved pairs, 1 row
    __shared__ unsigned short lidx[1024];
    __shared__ int   lcnt;
    __shared__ int   sred[4][4];
    __shared__ float fred[128][9];         // +1 pad -> stride 9, conflict-free

    int tid = threadIdx.x, blk = blockIdx.x;
    int wv = tid >> 6, lane = tid & 63;

    if (tid == 0) lcnt = 0;

    // (1) hoisted global loads: this row's pixels
    const float4* x04 = (const float4*)(x0) + (size_t)blk * 256;
    const float4* x14 = (const float4*)(x1) + (size_t)blk * 256;
    float4 va = x04[tid];
    float4 vb = x14[tid];

    int ft = tid & 31;         // feature group: ft, ft+32, ft+64, ft+96
    int cq = tid >> 5;         // col eighth (128 px)

    // (2) hoisted raw coefficient loads (independent of stats)
    float M2r[4], M3r[4], A0r[4], A1r[4], CPr[4];
    #pragma unroll
    for (int k = 0; k < 4; ++k) {
        int f = ft + 32 * k;
        M2r[k] = wsf[64 + 2 * DD + f];
        M3r[k] = wsf[64 + 3 * DD + f];
        A0r[k] = wsf[64 + 0 * DD + f];
        A1r[k] = wsf[64 + 1 * DD + f];
        CPr[k] = wsf[576 + f];
    }

    // (3) stats pre-reduce (latency of (1)/(2) hides under this)
    int rmn = wsi[RMINP + tid], rmx = wsi[RMAXP + tid];
    int cmn = wsi[CMINP + tid], cmx = wsi[CMAXP + tid];
    for (int off = 32; off >= 1; off >>= 1) {
        rmn = min(rmn, __shfl_xor(rmn, off, 64));
        rmx = max(rmx, __shfl_xor(rmx, off, 64));
        cmn = min(cmn, __shfl_xor(cmn, off, 64));
        cmx = max(cmx, __shfl_xor(cmx, off, 64));
    }
    if (lane == 0) {
        sred[wv][0] = rmn; sred[wv][1] = rmx;
        sred[wv][2] = cmn; sred[wv][3] = cmx;
    }
    __syncthreads();   // sred + lcnt visible
    rmn = min(min(sred[0][0], sred[1][0]), min(sred[2][0], sred[3][0]));
    rmx = max(max(sred[0][1], sred[1][1]), max(sred[2][1], sred[3][1]));
    cmn = min(min(sred[0][2], sred[1][2]), min(sred[2][2], sred[3][2]));
    cmx = max(max(sred[0][3], sred[1][3]), max(sred[2][3], sred[3][3]));

    // (4) stage (register data long since arrived); record exact-zero pixels
    float4* sv4 = (float4*)sv_f;
    {
        sv4[2 * tid]     = make_float4(va.x, va.y, vb.x, vb.y);
        sv4[2 * tid + 1] = make_float4(va.z, va.w, vb.z, vb.w);
        int p4 = 4 * tid;
        if (va.x == 0.f) { int p = atomicAdd(&lcnt, 1); lidx[p] = (unsigned short)(p4 + 0); }
        if (va.y == 0.f) { int p = atomicAdd(&lcnt, 1); lidx[p] = (unsigned short)(p4 + 1); }
        if (va.z == 0.f) { int p = atomicAdd(&lcnt, 1); lidx[p] = (unsigned short)(p4 + 2); }
        if (va.w == 0.f) { int p = atomicAdd(&lcnt, 1); lidx[p] = (unsigned short)(p4 + 3); }
    }
    __syncthreads();

    // (5) finalize coefficients
    int row = blk;
    float rs = 1.0f / (float)(rmx - rmn);
    float cs = 1.0f / (float)(cmx - cmn);

    f32x2 M2v[4], M3v[4], tv[4], st[4], acc[4];
    float a1v[4], rb[4], accsub[4];
    #pragma unroll
    for (int k = 0; k < 4; ++k) {
        float a0 = A0r[k] * rs;
        float a1 = A1r[k] * cs;
        float cp = CPr[k] - (float)rmn * a0 - (float)cmn * a1;
        rb[k]  = fmaf((float)row, a0, cp);
        a1v[k] = a1;
        float tA = fmaf((float)(cq * 128), a1, rb[k]);
        M2v[k].x = M2r[k]; M2v[k].y = M2r[k];
        M3v[k].x = M3r[k]; M3v[k].y = M3r[k];
        tv[k].x = tA; tv[k].y = tA + a1;
        st[k].x = a1 + a1; st[k].y = a1 + a1;
        acc[k].x = 0.f; acc[k].y = 0.f;
        accsub[k] = 0.f;
    }

    // (6) hot loop: 64 float4 (2 px each), 4 features, guaranteed-packed math
    const float4* p = sv4 + cq * 64;
    #pragma unroll 8
    for (int q = 0; q < 64; ++q) {
        float4 v = p[q];      // 2 px; wave reads 2 uniform addrs -> broadcast
        f32x2 v0; v0.x = v.x; v0.y = v.y;
        f32x2 v1; v1.x = v.z; v1.y = v.w;
        #pragma unroll
        for (int k = 0; k < 4; ++k) {
            f32x2 d = pk_fma(v0, M2v[k], pk_fma(v1, M3v[k], tv[k]));
            f32x2 r; r.x = fmaxf(d.x, 0.f); r.y = fmaxf(d.y, 0.f);
            acc[k] = pk_add(acc[k], r);
            tv[k]  = pk_add(tv[k], st[k]);
        }
    }

    int nz = lcnt;             // subtract masked-out (zero) pixels
    for (int ii = 0; ii < nz; ++ii) {
        int px = lidx[ii];
        if ((px >> 7) == cq) {
            float v0 = sv_f[(px >> 1) * 4 + (px & 1)];
            float v1 = sv_f[(px >> 1) * 4 + 2 + (px & 1)];
            #pragma unroll
            for (int k = 0; k < 4; ++k) {
                float tp = fmaf((float)px, a1v[k], rb[k]);
                accsub[k] += fmaxf(fmaf(v0, M2v[k].x, fmaf(v1, M3v[k].x, tp)), 0.f);
            }
        }
    }

    #pragma unroll
    for (int k = 0; k < 4; ++k)
        fred[ft + 32 * k][cq] = (acc[k].x + acc[k].y) - accsub[k];
    __syncthreads();
    if (tid < 128) {
        const float* fr = fred[tid];
        float s = ((fr[0] + fr[1]) + (fr[2] + fr[3]))
                + ((fr[4] + fr[5]) + (fr[6] + fr[7]));
        wsf[PART + (size_t)tid * NBB + blk] = s;   // [feature][block]
    }
}

// ---- kC: 128 blocks, one feature each: reduce + mean + matvec-atomics ------
__global__ __launch_bounds__(256) void kC(const float* __restrict__ wsf,
                                          const int* __restrict__ wsi,
                                          const float* __restrict__ W3,
                                          float* __restrict__ out) {
    __shared__ float sred[4];
    __shared__ int   cred[4];
    __shared__ float mf_sh;
    int f = blockIdx.x, tid = threadIdx.x;
    int wv = tid >> 6, lane = tid & 63;

    // total mask count (256 per-stats-block counts)
    int c = wsi[CNTP + tid];
    for (int off = 32; off >= 1; off >>= 1) c += __shfl_xor(c, off, 64);
    if (lane == 0) cred[wv] = c;

    // per-feature sum over 1024 block-partials (contiguous -> coalesced)
    const float4* p = (const float4*)(wsf + PART + (size_t)f * NBB);
    float4 v = p[tid];
    float S = (v.x + v.y) + (v.z + v.w);
    for (int off = 32; off >= 1; off >>= 1) S += __shfl_xor(S, off, 64);
    if (lane == 0) sred[wv] = S;
    __syncthreads();
    if (tid == 0) {
        float tot = (sred[0] + sred[1]) + (sred[2] + sred[3]);
        float cnt = (float)(cred[0] + cred[1] + cred[2] + cred[3]);
        mf_sh = tot / cnt;
    }
    __syncthreads();

    // out[j] += m_f * W3[f][j]  (row contiguous; 128 distinct addresses)
    if (tid < 128) {
        float mf = mf_sh;
        atomicAdd(&out[tid], mf * W3[f * DD + tid]);
    }
}

extern "C" void kernel_launch(void* const* d_in, const int* in_sizes, int n_in,
                              void* d_out, int out_size, void* d_ws, size_t ws_size,
                              hipStream_t stream) {
    const float* x  = (const float*)d_in[0];
    const float* x0 = x;
    const float* x1 = x + NPIX;
    const float* W1 = (const float*)d_in[1];
    const float* b1 = (const float*)d_in[2];
    const float* W2 = (const float*)d_in[3];
    const float* b2 = (const float*)d_in[4];
    const float* W3 = (const float*)d_in[5];
    const float* b3 = (const float*)d_in[6];
    float* outp = (float*)d_out;
    float* wsf  = (float*)d_ws;
    int*   wsi  = (int*)d_ws;

    hipLaunchKernelGGL(kA, dim3(NSB + 1), dim3(256), 0, stream,
                       x0, x1, W1, b1, W2, b2, b3, outp, wsf, wsi);
    hipLaunchKernelGGL(kB, dim3(NBB), dim3(256), 0, stream, x0, x1, wsf, wsi);
    hipLaunchKernelGGL(kC, dim3(DD), dim3(256), 0, stream, wsf, wsi, W3, outp);
}

// Round 21
// 30.885 us; speedup vs baseline: 1.3938x; 1.1197x over previous
//
#include <hip/hip_runtime.h>
#include <climits>

#define HH 1024
#define WW 1024
#define DD 128
#define NPIX (HH * WW)
#define NSB 256    // stats blocks (4 rows each) in kA
#define NBB 1024   // main blocks (1 row each) in kB

// FINAL (plateau): best-measured configuration, round 14, 30.28 us.
// Budget (measured by duplication experiments R15/R19): kA ~3, kB ~15.5,
// tail ~5.5, boundaries ~0-3. Session lessons: kernel boundaries are the
// cheapest grid sync on MI355X (grid.sync ~tens of us; same-address device
// atomics ~100ns/writer serialized); L3 pre-warming of the NEXT kernel's
// input (+x1 here) is worth ~1 us; tail cost is form-invariant (latency
// floor, not contention).

// ws 4B-unit layout:
//   wsf[64..576)    M (4x128 row-major)
//   wsf[576..704)   c (128)
//   wsi[1024..1280) rminP | [1280..1536) rmaxP | [1536..1792) cminP
//   wsi[1792..2048) cmaxP | [2048..2304) cntP     (one per stats block)
//   wsf[6400..6656) x1-warm dummies
//   wsf[8192..8192+128*1024) partials, layout [feature][block]
#define RMINP 1024
#define RMAXP 1280
#define CMINP 1536
#define CMAXP 1792
#define CNTP  2048
#define PART  8192

typedef __attribute__((ext_vector_type(2))) float f32x2;

// ---- stats for a block's 4 rows --------------------------------------------
__device__ __forceinline__ void d_stats(const float* __restrict__ x0, int blk,
                                        int tid, int* __restrict__ wsi,
                                        int (*sred)[8]) {
    const float4* x4 = (const float4*)(x0) + (size_t)blk * 1024;
    int any0, any1, any2, any3;
    int cmn = INT_MAX, cmx = -1, cnt = 0;
    int c4 = 4 * tid;
    {
        float4 v;
        bool z0, z1, z2, z3;
        #define STAT_K(K, ANY)                                                 \
            v = x4[K * 256 + tid];                                             \
            z0 = v.x != 0.f; z1 = v.y != 0.f; z2 = v.z != 0.f; z3 = v.w != 0.f;\
            ANY = (int)(z0 | z1 | z2 | z3);                                    \
            if (ANY) {                                                         \
                cmn = min(cmn, z0 ? c4 : (z1 ? c4+1 : (z2 ? c4+2 : c4+3)));    \
                cmx = max(cmx, z3 ? c4+3 : (z2 ? c4+2 : (z1 ? c4+1 : c4)));    \
            }                                                                  \
            cnt += (int)z0 + (int)z1 + (int)z2 + (int)z3;
        STAT_K(0, any0) STAT_K(1, any1) STAT_K(2, any2) STAT_K(3, any3)
        #undef STAT_K
    }
    for (int off = 32; off >= 1; off >>= 1) {
        cmn = min(cmn, __shfl_xor(cmn, off, 64));
        cmx = max(cmx, __shfl_xor(cmx, off, 64));
        cnt += __shfl_xor(cnt, off, 64);
        any0 |= __shfl_xor(any0, off, 64);
        any1 |= __shfl_xor(any1, off, 64);
        any2 |= __shfl_xor(any2, off, 64);
        any3 |= __shfl_xor(any3, off, 64);
    }
    int wave = tid >> 6;
    if ((tid & 63) == 0) {
        sred[wave][0] = cmn; sred[wave][1] = cmx; sred[wave][2] = cnt;
        sred[wave][3] = any0; sred[wave][4] = any1;
        sred[wave][5] = any2; sred[wave][6] = any3;
    }
    __syncthreads();
    if (tid == 0) {
        int a = sred[0][0], b = sred[0][1], c = sred[0][2];
        int f0 = sred[0][3], f1 = sred[0][4], f2 = sred[0][5], f3 = sred[0][6];
        for (int w = 1; w < 4; ++w) {
            a = min(a, sred[w][0]); b = max(b, sred[w][1]); c += sred[w][2];
            f0 |= sred[w][3]; f1 |= sred[w][4]; f2 |= sred[w][5]; f3 |= sred[w][6];
        }
        int r0 = blk * 4;
        wsi[RMINP + blk] = f0 ? r0 : (f1 ? r0+1 : (f2 ? r0+2 : (f3 ? r0+3 : INT_MAX)));
        wsi[RMAXP + blk] = f3 ? r0+3 : (f2 ? r0+2 : (f1 ? r0+1 : (f0 ? r0 : -1)));
        wsi[CMINP + blk] = a;
        wsi[CMAXP + blk] = b;
        wsi[CNTP  + blk] = c;
    }
}

// ---- kA: 256 stats blocks (also warm x1 into L3) + 1 prep block ------------
__global__ __launch_bounds__(256) void kA(const float* __restrict__ x0,
                                          const float* __restrict__ x1,
                                          const float* __restrict__ W1,
                                          const float* __restrict__ b1,
                                          const float* __restrict__ W2,
                                          const float* __restrict__ b2,
                                          const float* __restrict__ b3,
                                          float* __restrict__ out,
                                          float* __restrict__ wsf,
                                          int* __restrict__ wsi) {
    __shared__ int sred[4][8];
    int blk = blockIdx.x, tid = threadIdx.x;
    if (blk < NSB) {
        d_stats(x0, blk, tid, wsi, sred);
        // warm this block's x1 rows into L3 (kB's staging then avoids HBM miss)
        const float4* y4 = (const float4*)(x1) + (size_t)blk * 1024;
        float s = 0.f;
        #pragma unroll
        for (int k = 0; k < 4; ++k) {
            float4 t4 = y4[k * 256 + tid];
            s += (t4.x + t4.y) + (t4.z + t4.w);
        }
        if (tid == 0) wsf[6400 + blk] = s;   // keep warm loads live
        return;
    }
    if (tid < 128) {
        int j = tid;
        float p0 = 0.f, p1 = 0.f, p2 = 0.f, p3 = 0.f, cc = 0.f;
        #pragma unroll 8
        for (int d = 0; d < DD; ++d) {
            float w2 = W2[d * DD + j];
            p0 = fmaf(W1[0 * DD + d], w2, p0);
            p1 = fmaf(W1[1 * DD + d], w2, p1);
            p2 = fmaf(W1[2 * DD + d], w2, p2);
            p3 = fmaf(W1[3 * DD + d], w2, p3);
            cc = fmaf(b1[d],          w2, cc);
        }
        wsf[64 + 0 * DD + j] = p0;
        wsf[64 + 1 * DD + j] = p1;
        wsf[64 + 2 * DD + j] = p2;
        wsf[64 + 3 * DD + j] = p3;
        wsf[576 + j] = cc + b2[j];
        out[j] = b3[j];              // seed output; kC accumulates atomically
    }
}

// ---- kB: main accumulate, 1 row/block, 4 features/thread, packed-f32 -------
// LDS layout per float4: (v0@px0, v0@px1, v1@px0, v1@px1) -> aligned f32 pairs
// for v_pk_fma_f32. Thread (ft=tid&31, cq=tid>>5): features {ft+32k},
// col-eighth cq (128 px = 64 pairs). Register-prefetch software pipeline.
__global__ __launch_bounds__(256) void kB(const float* __restrict__ x0,
                                          const float* __restrict__ x1,
                                          float* __restrict__ wsf,
                                          const int* __restrict__ wsi) {
    __shared__ float sv_f[4096];           // de-interleaved pairs, 1 row
    __shared__ unsigned short lidx[1024];
    __shared__ int   lcnt;
    __shared__ int   sred[4][4];
    __shared__ float fred[128][9];         // +1 pad -> stride 9, conflict-free

    int tid = threadIdx.x, blk = blockIdx.x;
    int wv = tid >> 6, lane = tid & 63;

    if (tid == 0) lcnt = 0;

    // reduce the 256 stats partials (one per thread)
    int rmn = wsi[RMINP + tid], rmx = wsi[RMAXP + tid];
    int cmn = wsi[CMINP + tid], cmx = wsi[CMAXP + tid];
    for (int off = 32; off >= 1; off >>= 1) {
        rmn = min(rmn, __shfl_xor(rmn, off, 64));
        rmx = max(rmx, __shfl_xor(rmx, off, 64));
        cmn = min(cmn, __shfl_xor(cmn, off, 64));
        cmx = max(cmx, __shfl_xor(cmx, off, 64));
    }
    if (lane == 0) {
        sred[wv][0] = rmn; sred[wv][1] = rmx;
        sred[wv][2] = cmn; sred[wv][3] = cmx;
    }
    __syncthreads();   // sred + lcnt visible
    rmn = min(min(sred[0][0], sred[1][0]), min(sred[2][0], sred[3][0]));
    rmx = max(max(sred[0][1], sred[1][1]), max(sred[2][1], sred[3][1]));
    cmn = min(min(sred[0][2], sred[1][2]), min(sred[2][2], sred[3][2]));
    cmx = max(max(sred[0][3], sred[1][3]), max(sred[2][3], sred[3][3]));

    // stage this row de-interleaved; record exact-zero pixels (rare)
    const float4* x04 = (const float4*)(x0) + (size_t)blk * 256;
    const float4* x14 = (const float4*)(x1) + (size_t)blk * 256;
    float4* sv4 = (float4*)sv_f;
    {
        float4 va = x04[tid];
        float4 vb = x14[tid];
        sv4[2 * tid]     = make_float4(va.x, va.y, vb.x, vb.y);
        sv4[2 * tid + 1] = make_float4(va.z, va.w, vb.z, vb.w);
        int p4 = 4 * tid;
        if (va.x == 0.f) { int p = atomicAdd(&lcnt, 1); lidx[p] = (unsigned short)(p4 + 0); }
        if (va.y == 0.f) { int p = atomicAdd(&lcnt, 1); lidx[p] = (unsigned short)(p4 + 1); }
        if (va.z == 0.f) { int p = atomicAdd(&lcnt, 1); lidx[p] = (unsigned short)(p4 + 2); }
        if (va.w == 0.f) { int p = atomicAdd(&lcnt, 1); lidx[p] = (unsigned short)(p4 + 3); }
    }
    __syncthreads();

    int ft = tid & 31;         // feature group: ft, ft+32, ft+64, ft+96
    int cq = tid >> 5;         // col eighth (128 px)
    int row = blk;
    float rs = 1.0f / (float)(rmx - rmn);
    float cs = 1.0f / (float)(cmx - cmn);

    f32x2 M2v[4], M3v[4], tv[4], st[4], acc[4];
    float a1v[4], rb[4];
    float accsub[4];
    #pragma unroll
    for (int k = 0; k < 4; ++k) {
        int f = ft + 32 * k;
        float M2 = wsf[64 + 2 * DD + f];
        float M3 = wsf[64 + 3 * DD + f];
        float a0 = wsf[64 + 0 * DD + f] * rs;
        float a1 = wsf[64 + 1 * DD + f] * cs;
        float cp = wsf[576 + f] - (float)rmn * a0 - (float)cmn * a1;
        rb[k]  = fmaf((float)row, a0, cp);
        a1v[k] = a1;
        float tA = fmaf((float)(cq * 128), a1, rb[k]);
        M2v[k] = (f32x2)M2;
        M3v[k] = (f32x2)M3;
        tv[k].x = tA; tv[k].y = tA + a1;
        st[k] = (f32x2)(a1 + a1);
        acc[k] = (f32x2)0.f;
        accsub[k] = 0.f;
    }

    const float4* p = sv4 + cq * 64;
    float4 vq = p[0];                       // software-pipelined LDS read
    #pragma unroll 4
    for (int q = 0; q < 64; ++q) {
        float4 vn = p[(q + 1) & 63];        // prefetch next (wraps, harmless)
        f32x2 v0; v0.x = vq.x; v0.y = vq.y;
        f32x2 v1; v1.x = vq.z; v1.y = vq.w;
        #pragma unroll
        for (int k = 0; k < 4; ++k) {
            f32x2 d = __builtin_elementwise_fma(v0, M2v[k],
                        __builtin_elementwise_fma(v1, M3v[k], tv[k]));
            f32x2 r = __builtin_elementwise_max(d, (f32x2)0.f);
            acc[k] += r;           // v_pk_add_f32
            tv[k] += st[k];        // v_pk_add_f32
        }
        vq = vn;
    }

    int nz = lcnt;             // subtract masked-out (zero) pixels
    for (int ii = 0; ii < nz; ++ii) {
        int px = lidx[ii];
        if ((px >> 7) == cq) {
            float v0 = sv_f[(px >> 1) * 4 + (px & 1)];
            float v1 = sv_f[(px >> 1) * 4 + 2 + (px & 1)];
            #pragma unroll
            for (int k = 0; k < 4; ++k) {
                float tp = fmaf((float)px, a1v[k], rb[k]);
                accsub[k] += fmaxf(fmaf(v0, M2v[k].x, fmaf(v1, M3v[k].x, tp)), 0.f);
            }
        }
    }

    #pragma unroll
    for (int k = 0; k < 4; ++k)
        fred[ft + 32 * k][cq] = (acc[k].x + acc[k].y) - accsub[k];
    __syncthreads();
    if (tid < 128) {
        const float* fr = fred[tid];
        float s = ((fr[0] + fr[1]) + (fr[2] + fr[3]))
                + ((fr[4] + fr[5]) + (fr[6] + fr[7]));
        wsf[PART + (size_t)tid * NBB + blk] = s;
    }
}

// ---- kC: 128 blocks, one feature each: reduce + mean + matvec-atomics ------
__global__ __launch_bounds__(256) void kC(const float* __restrict__ wsf,
                                          const int* __restrict__ wsi,
                                          const float* __restrict__ W3,
                                          float* __restrict__ out) {
    __shared__ float sred[4];
    __shared__ int   cred[4];
    __shared__ float mf_sh;
    int f = blockIdx.x, tid = threadIdx.x;
    int wv = tid >> 6, lane = tid & 63;

    // total mask count (256 per-stats-block counts)
    int c = wsi[CNTP + tid];
    for (int off = 32; off >= 1; off >>= 1) c += __shfl_xor(c, off, 64);
    if (lane == 0) cred[wv] = c;

    // per-feature sum over 1024 block-partials (contiguous -> coalesced)
    const float4* p = (const float4*)(wsf + PART + (size_t)f * NBB);
    float4 v = p[tid];
    float S = (v.x + v.y) + (v.z + v.w);
    for (int off = 32; off >= 1; off >>= 1) S += __shfl_xor(S, off, 64);
    if (lane == 0) sred[wv] = S;
    __syncthreads();
    if (tid == 0) {
        float tot = (sred[0] + sred[1]) + (sred[2] + sred[3]);
        float cnt = (float)(cred[0] + cred[1] + cred[2] + cred[3]);
        mf_sh = tot / cnt;
    }
    __syncthreads();

    // out[j] += m_f * W3[f][j]  (row contiguous; 128 distinct addresses)
    if (tid < 128) {
        float mf = mf_sh;
        atomicAdd(&out[tid], mf * W3[f * DD + tid]);
    }
}

extern "C" void kernel_launch(void* const* d_in, const int* in_sizes, int n_in,
                              void* d_out, int out_size, void* d_ws, size_t ws_size,
                              hipStream_t stream) {
    const float* x  = (const float*)d_in[0];
    const float* x0 = x;
    const float* x1 = x + NPIX;
    const float* W1 = (const float*)d_in[1];
    const float* b1 = (const float*)d_in[2];
    const float* W2 = (const float*)d_in[3];
    const float* b2 = (const float*)d_in[4];
    const float* W3 = (const float*)d_in[5];
    const float* b3 = (const float*)d_in[6];
    float* outp = (float*)d_out;
    float* wsf  = (float*)d_ws;
    int*   wsi  = (int*)d_ws;

    hipLaunchKernelGGL(kA, dim3(NSB + 1), dim3(256), 0, stream,
                       x0, x1, W1, b1, W2, b2, b3, outp, wsf, wsi);
    hipLaunchKernelGGL(kB, dim3(NBB), dim3(256), 0, stream, x0, x1, wsf, wsi);
    hipLaunchKernelGGL(kC, dim3(DD), dim3(256), 0, stream, wsf, wsi, W3, outp);
}